// Round 7
// baseline (275.726 us; speedup 1.0000x reference)
//
#include <hip/hip_runtime.h>
#include <float.h>
#include <math.h>

#define DIM    1024
#define NROWS  131072
#define TOPK   32
#define TAU    0.2f
#define CHUNK  512
#define NCHUNK (NROWS / CHUNK)   // 256
#define NCAND  (NCHUNK * TOPK)   // 8192

#define LOG_BLOCKS 2048
#define ROWS_PER_WAVE 16         // 2 rows/iter x 8 iters
#define NITER 8

// Native clang vector type (HIP_vector_type<float,4> is a struct and is
// rejected by __builtin_nontemporal_load).
typedef float floatx4 __attribute__((ext_vector_type(4)));

// Non-temporal 16B load: emits global_load_dwordx4 ... nt.
__device__ __forceinline__ floatx4 ld_nt(const float* p) {
    return __builtin_nontemporal_load(reinterpret_cast<const floatx4*>(p));
}

// ---------------------------------------------------------------------------
// MEASUREMENT PROBE (4-pass, striped): touches 2 GB so its dispatch outranks
// the ~320us harness fills and lands in the rocprof top-5 WITH its own
// FETCH_SIZE / hbm_gbps. Wave g reads rows {g, g+8192, ...}: concurrently
// resident waves sweep a contiguous ~32MB window (DRAM page locality test).
// Pass 2..4 re-read the same rows (L3 re-read-service test via FETCH_SIZE).
// ---------------------------------------------------------------------------
__global__ __launch_bounds__(256) void read_probe4_kernel(const float* __restrict__ Km,
                                                          float* __restrict__ dummy) {
    const int t    = threadIdx.x;
    const int lane = t & 63;
    const int wave = t >> 6;
    const int gwave = blockIdx.x * 4 + wave;   // 0..8191

    float a0 = 0.f, a1 = 0.f, a2 = 0.f, a3 = 0.f;
    #pragma unroll 1
    for (int pass = 0; pass < 4; ++pass) {
        const float* base = Km + (size_t)gwave * DIM + lane * 4;
        floatx4 b[2][4];
        #pragma unroll
        for (int j = 0; j < 4; ++j) b[0][j] = ld_nt(base + j * 256);
        #pragma unroll
        for (int w = 0; w < 16; ++w) {
            const float* nbase = base + (size_t)8192 * DIM;   // next striped row
            if (w < 15) {
                #pragma unroll
                for (int j = 0; j < 4; ++j) b[(w + 1) & 1][j] = ld_nt(nbase + j * 256);
            }
            #pragma unroll
            for (int j = 0; j < 4; ++j) {
                floatx4 kv = b[w & 1][j];
                a0 += kv.x; a1 += kv.y; a2 += kv.z; a3 += kv.w;
            }
            base = nbase;
        }
    }
    if (lane == 0) dummy[gwave] = (a0 + a1) + (a2 + a3);
}

// ---------------------------------------------------------------------------
// Kernel 1: logits[row] = dot(K[row], query). UNCHANGED from round 5.
// ---------------------------------------------------------------------------
__global__ __launch_bounds__(256) void logits_kernel(const float* __restrict__ Km,
                                                     const float* __restrict__ q,
                                                     float* __restrict__ logits,
                                                     float* __restrict__ full_attn) {
    const int t    = threadIdx.x;
    const int lane = t & 63;
    const int wave = t >> 6;
    const int sub  = lane & 31;
    const int rsel = lane >> 5;

    floatx4 qv[8];
    #pragma unroll
    for (int p = 0; p < 8; ++p)
        qv[p] = *reinterpret_cast<const floatx4*>(q + p * 128 + sub * 4);

    const int gwave = blockIdx.x * 4 + wave;
    const int rbase = gwave * ROWS_PER_WAVE;
    const float* kptr = Km + (size_t)(rbase + rsel) * DIM + sub * 4;

    floatx4 buf[2][8];
    #pragma unroll
    for (int p = 0; p < 8; ++p)
        buf[0][p] = ld_nt(kptr + p * 128);

    #pragma unroll
    for (int r = 0; r < NITER; ++r) {
        const float* knext = kptr + 2 * DIM;
        if (r < NITER - 1) {
            #pragma unroll
            for (int p = 0; p < 8; ++p)
                buf[(r + 1) & 1][p] = ld_nt(knext + p * 128);
        }
        float a0 = 0.f, a1 = 0.f, a2 = 0.f, a3 = 0.f;
        #pragma unroll
        for (int p = 0; p < 8; ++p) {
            floatx4 kv = buf[r & 1][p];
            floatx4 qq = qv[p];
            a0 = fmaf(kv.x, qq.x, a0);
            a1 = fmaf(kv.y, qq.y, a1);
            a2 = fmaf(kv.z, qq.z, a2);
            a3 = fmaf(kv.w, qq.w, a3);
        }
        float acc = (a0 + a1) + (a2 + a3);
        #pragma unroll
        for (int off = 1; off < 32; off <<= 1) acc += __shfl_xor(acc, off, 64);
        if (sub == 0) {
            const int row = rbase + 2 * r + rsel;
            logits[row]    = acc;
            full_attn[row] = 0.f;
        }
        kptr = knext;
    }
}

// ---------------------------------------------------------------------------
// Kernel 2: per-block (1 wave) local top-32 of a 512-element chunk. UNCHANGED.
// ---------------------------------------------------------------------------
__global__ __launch_bounds__(64) void topk_local_kernel(const float* __restrict__ logits,
                                                        float* __restrict__ cand_val,
                                                        int* __restrict__ cand_idx) {
    const int lane = threadIdx.x;
    const int base = blockIdx.x * CHUNK;

    float v[8]; int gi[8];
    floatx4 a = *reinterpret_cast<const floatx4*>(logits + base + lane * 4);
    floatx4 b = *reinterpret_cast<const floatx4*>(logits + base + 256 + lane * 4);
    v[0] = a.x; v[1] = a.y; v[2] = a.z; v[3] = a.w;
    v[4] = b.x; v[5] = b.y; v[6] = b.z; v[7] = b.w;
    #pragma unroll
    for (int j = 0; j < 4; ++j) gi[j] = base + lane * 4 + j;
    #pragma unroll
    for (int j = 0; j < 4; ++j) gi[4 + j] = base + 256 + lane * 4 + j;

    for (int r = 0; r < TOPK; ++r) {
        float m = v[0]; int mi = gi[0];
        #pragma unroll
        for (int j = 1; j < 8; ++j)
            if (v[j] > m || (v[j] == m && gi[j] < mi)) { m = v[j]; mi = gi[j]; }
        #pragma unroll
        for (int off = 32; off > 0; off >>= 1) {
            float ov = __shfl_xor(m, off, 64);
            int   oi = __shfl_xor(mi, off, 64);
            if (ov > m || (ov == m && oi < mi)) { m = ov; mi = oi; }
        }
        #pragma unroll
        for (int j = 0; j < 8; ++j)
            if (gi[j] == mi) v[j] = -FLT_MAX;
        if (lane == 0) {
            cand_val[blockIdx.x * TOPK + r] = m;
            cand_idx[blockIdx.x * TOPK + r] = mi;
        }
    }
}

// ---------------------------------------------------------------------------
// Kernel 3: scale, global top-32, softmax, scatter, out = attn @ V. UNCHANGED.
// ---------------------------------------------------------------------------
__global__ __launch_bounds__(256) void final_kernel(const float* __restrict__ cand_val,
                                                    const int* __restrict__ cand_idx,
                                                    const float* __restrict__ q,
                                                    const float* __restrict__ Vm,
                                                    float* __restrict__ out,
                                                    float* __restrict__ full_attn) {
    const int t = threadIdx.x;
    const int lane = t & 63, wave = t >> 6;
    __shared__ float wred_v[4];
    __shared__ int   wred_i[4];
    __shared__ float tval[TOPK];
    __shared__ int   tidx[TOPK];
    __shared__ float attn_s[TOPK];
    __shared__ float red4[4];
    __shared__ float scale_s;

    float ss = 0.f;
    for (int i = t; i < DIM; i += 256) { float vq = q[i]; ss = fmaf(vq, vq, ss); }
    #pragma unroll
    for (int off = 32; off > 0; off >>= 1) ss += __shfl_xor(ss, off, 64);
    if (lane == 0) red4[wave] = ss;
    __syncthreads();
    if (t == 0) {
        float s = red4[0] + red4[1] + red4[2] + red4[3];
        scale_s = 1.0f / (fmaxf(sqrtf(s), 1e-12f) * TAU);
    }

    float v[32]; int gi[32];
    #pragma unroll
    for (int k = 0; k < 32; ++k) {
        int c = t + 256 * k;
        v[k]  = cand_val[c];
        gi[k] = cand_idx[c];
    }
    float m = v[0]; int mi = gi[0];
    #pragma unroll
    for (int k = 1; k < 32; ++k)
        if (v[k] > m || (v[k] == m && gi[k] < mi)) { m = v[k]; mi = gi[k]; }

    __syncthreads();

    for (int r = 0; r < TOPK; ++r) {
        float wm = m; int wmi = mi;
        #pragma unroll
        for (int off = 32; off > 0; off >>= 1) {
            float ov = __shfl_xor(wm, off, 64);
            int   oi = __shfl_xor(wmi, off, 64);
            if (ov > wm || (ov == wm && oi < wmi)) { wm = ov; wmi = oi; }
        }
        if (lane == 0) { wred_v[wave] = wm; wred_i[wave] = wmi; }
        __syncthreads();
        float gm = wred_v[0]; int gmi = wred_i[0];
        #pragma unroll
        for (int w = 1; w < 4; ++w) {
            float ov = wred_v[w]; int oi = wred_i[w];
            if (ov > gm || (ov == gm && oi < gmi)) { gm = ov; gmi = oi; }
        }
        if (t == 0) { tval[r] = gm; tidx[r] = gmi; }
        if (mi == gmi) {
            #pragma unroll
            for (int k = 0; k < 32; ++k)
                if (gi[k] == gmi) v[k] = -FLT_MAX;
            m = v[0]; mi = gi[0];
            #pragma unroll
            for (int k = 1; k < 32; ++k)
                if (v[k] > m || (v[k] == m && gi[k] < mi)) { m = v[k]; mi = gi[k]; }
        }
        __syncthreads();
    }

    const float scale = scale_s;
    float sum = 0.f;
    #pragma unroll
    for (int j = 0; j < TOPK; ++j) sum += expf((tval[j] - tval[0]) * scale);
    if (t < TOPK) attn_s[t] = expf((tval[t] - tval[0]) * scale) / sum;
    __syncthreads();

    if (t < TOPK) full_attn[tidx[t]] = attn_s[t];

    for (int d = t; d < DIM; d += 256) {
        float acc = 0.f;
        #pragma unroll
        for (int j = 0; j < TOPK; ++j)
            acc = fmaf(attn_s[j], Vm[(size_t)tidx[j] * DIM + d], acc);
        out[d] = acc;
    }
}

// ---------------------------------------------------------------------------
extern "C" void kernel_launch(void* const* d_in, const int* in_sizes, int n_in,
                              void* d_out, int out_size, void* d_ws, size_t ws_size,
                              hipStream_t stream) {
    const float* q  = (const float*)d_in[0];
    const float* Km = (const float*)d_in[1];
    const float* Vm = (const float*)d_in[2];

    float* out       = (float*)d_out;       // [0 .. 1024)
    float* full_attn = out + DIM;           // [1024 .. 1024+131072)

    float* logits   = (float*)d_ws;                 // NROWS floats
    float* cand_val = logits + NROWS;               // NCAND floats
    int*   cand_idx = (int*)(cand_val + NCAND);     // NCAND ints
    float* dummy    = (float*)(cand_idx + NCAND);   // 8192 floats (probe sink)

    // measurement probe FIRST (writes only ws scratch; 2 GB touched so its
    // dispatch outranks the harness fills and exposes FETCH/hbm counters)
    read_probe4_kernel<<<LOG_BLOCKS, 256, 0, stream>>>(Km, dummy);
    logits_kernel<<<LOG_BLOCKS, 256, 0, stream>>>(Km, q, logits, full_attn);
    topk_local_kernel<<<NCHUNK, 64, 0, stream>>>(logits, cand_val, cand_idx);
    final_kernel<<<1, 256, 0, stream>>>(cand_val, cand_idx, q, Vm, out, full_attn);
}

// Round 8
// 210.908 us; speedup vs baseline: 1.3073x; 1.3073x over previous
//
#include <hip/hip_runtime.h>
#include <float.h>
#include <math.h>

#define DIM    1024
#define NROWS  131072
#define TOPK   32
#define TAU    0.2f
#define CHUNK  512
#define NCHUNK (NROWS / CHUNK)   // 256
#define NCAND  (NCHUNK * TOPK)   // 8192

#define NWAVES 8192              // phase-A waves (2048 blocks x 4)
#define WSTEPS 16                // rows per wave, striped by NWAVES

typedef float floatx4 __attribute__((ext_vector_type(4)));

__device__ __forceinline__ floatx4 ld_nt(const float* p) {
    return __builtin_nontemporal_load(reinterpret_cast<const floatx4*>(p));
}

// ---------------------------------------------------------------------------
// Phase A: faithful clone of the 5.8TB/s striped read probe, with the dot
// folded in as per-lane FMAs. Wave g reads rows {g, g+8192, ...} (resident
// waves sweep one contiguous ~32MB window together). NO cross-lane ops, no
// mid-loop stores: 64 per-lane partials per row go to ws at the end.
// partial[row*64 + lane] = sum_j K[row][lane*4 + j*256 + c] * q[same]
// ---------------------------------------------------------------------------
__global__ __launch_bounds__(256) void logitsA_kernel(const float* __restrict__ Km,
                                                      const float* __restrict__ q,
                                                      float* __restrict__ partial) {
    const int t    = threadIdx.x;
    const int lane = t & 63;
    const int wave = t >> 6;
    const int gwave = blockIdx.x * 4 + wave;   // 0..8191

    floatx4 qv[4];
    #pragma unroll
    for (int j = 0; j < 4; ++j)
        qv[j] = *reinterpret_cast<const floatx4*>(q + j * 256 + lane * 4);

    const float* base = Km + (size_t)gwave * DIM + lane * 4;
    floatx4 b[2][4];
    #pragma unroll
    for (int j = 0; j < 4; ++j) b[0][j] = ld_nt(base + j * 256);

    float part[WSTEPS];
    #pragma unroll
    for (int w = 0; w < WSTEPS; ++w) {
        const float* nbase = base + (size_t)NWAVES * DIM;   // next striped row
        if (w < WSTEPS - 1) {
            #pragma unroll
            for (int j = 0; j < 4; ++j) b[(w + 1) & 1][j] = ld_nt(nbase + j * 256);
        }
        float a0 = 0.f, a1 = 0.f, a2 = 0.f, a3 = 0.f;
        #pragma unroll
        for (int j = 0; j < 4; ++j) {
            floatx4 kv = b[w & 1][j];
            floatx4 qq = qv[j];
            a0 = fmaf(kv.x, qq.x, a0);
            a1 = fmaf(kv.y, qq.y, a1);
            a2 = fmaf(kv.z, qq.z, a2);
            a3 = fmaf(kv.w, qq.w, a3);
        }
        part[w] = (a0 + a1) + (a2 + a3);
        base = nbase;
    }
    // all stores after the load stream (coalesced 256B per wave per row)
    #pragma unroll
    for (int w = 0; w < WSTEPS; ++w)
        partial[(size_t)(gwave + NWAVES * w) * 64 + lane] = part[w];
}

// ---------------------------------------------------------------------------
// Phase B: logits[row] = sum of 64 partials; also zeroes full_attn[row].
// 16 lanes per row via float4 load + 4-step shfl. 32 rows per wave.
// ---------------------------------------------------------------------------
__global__ __launch_bounds__(256) void reduceB_kernel(const float* __restrict__ partial,
                                                      float* __restrict__ logits,
                                                      float* __restrict__ full_attn) {
    const int t    = threadIdx.x;
    const int lane = t & 63;
    const int wave = t >> 6;
    const int gw   = blockIdx.x * 4 + wave;    // 0..4095
    const int rowbase = gw * 32;

    #pragma unroll
    for (int it = 0; it < 8; ++it) {
        const int row = rowbase + it * 4 + (lane >> 4);
        floatx4 v = *reinterpret_cast<const floatx4*>(partial + (size_t)row * 64 + (lane & 15) * 4);
        float s = (v.x + v.y) + (v.z + v.w);
        #pragma unroll
        for (int off = 1; off < 16; off <<= 1) s += __shfl_xor(s, off, 64);
        if ((lane & 15) == 0) {
            logits[row]    = s;
            full_attn[row] = 0.f;
        }
    }
}

// ---------------------------------------------------------------------------
// Kernel 2: per-block (1 wave) local top-32 of a 512-element chunk. UNCHANGED.
// ---------------------------------------------------------------------------
__global__ __launch_bounds__(64) void topk_local_kernel(const float* __restrict__ logits,
                                                        float* __restrict__ cand_val,
                                                        int* __restrict__ cand_idx) {
    const int lane = threadIdx.x;
    const int base = blockIdx.x * CHUNK;

    float v[8]; int gi[8];
    floatx4 a = *reinterpret_cast<const floatx4*>(logits + base + lane * 4);
    floatx4 b = *reinterpret_cast<const floatx4*>(logits + base + 256 + lane * 4);
    v[0] = a.x; v[1] = a.y; v[2] = a.z; v[3] = a.w;
    v[4] = b.x; v[5] = b.y; v[6] = b.z; v[7] = b.w;
    #pragma unroll
    for (int j = 0; j < 4; ++j) gi[j] = base + lane * 4 + j;
    #pragma unroll
    for (int j = 0; j < 4; ++j) gi[4 + j] = base + 256 + lane * 4 + j;

    for (int r = 0; r < TOPK; ++r) {
        float m = v[0]; int mi = gi[0];
        #pragma unroll
        for (int j = 1; j < 8; ++j)
            if (v[j] > m || (v[j] == m && gi[j] < mi)) { m = v[j]; mi = gi[j]; }
        #pragma unroll
        for (int off = 32; off > 0; off >>= 1) {
            float ov = __shfl_xor(m, off, 64);
            int   oi = __shfl_xor(mi, off, 64);
            if (ov > m || (ov == m && oi < mi)) { m = ov; mi = oi; }
        }
        #pragma unroll
        for (int j = 0; j < 8; ++j)
            if (gi[j] == mi) v[j] = -FLT_MAX;
        if (lane == 0) {
            cand_val[blockIdx.x * TOPK + r] = m;
            cand_idx[blockIdx.x * TOPK + r] = mi;
        }
    }
}

// ---------------------------------------------------------------------------
// Kernel 3: scale, global top-32, softmax, scatter, out = attn @ V. UNCHANGED.
// ---------------------------------------------------------------------------
__global__ __launch_bounds__(256) void final_kernel(const float* __restrict__ cand_val,
                                                    const int* __restrict__ cand_idx,
                                                    const float* __restrict__ q,
                                                    const float* __restrict__ Vm,
                                                    float* __restrict__ out,
                                                    float* __restrict__ full_attn) {
    const int t = threadIdx.x;
    const int lane = t & 63, wave = t >> 6;
    __shared__ float wred_v[4];
    __shared__ int   wred_i[4];
    __shared__ float tval[TOPK];
    __shared__ int   tidx[TOPK];
    __shared__ float attn_s[TOPK];
    __shared__ float red4[4];
    __shared__ float scale_s;

    float ss = 0.f;
    for (int i = t; i < DIM; i += 256) { float vq = q[i]; ss = fmaf(vq, vq, ss); }
    #pragma unroll
    for (int off = 32; off > 0; off >>= 1) ss += __shfl_xor(ss, off, 64);
    if (lane == 0) red4[wave] = ss;
    __syncthreads();
    if (t == 0) {
        float s = red4[0] + red4[1] + red4[2] + red4[3];
        scale_s = 1.0f / (fmaxf(sqrtf(s), 1e-12f) * TAU);
    }

    float v[32]; int gi[32];
    #pragma unroll
    for (int k = 0; k < 32; ++k) {
        int c = t + 256 * k;
        v[k]  = cand_val[c];
        gi[k] = cand_idx[c];
    }
    float m = v[0]; int mi = gi[0];
    #pragma unroll
    for (int k = 1; k < 32; ++k)
        if (v[k] > m || (v[k] == m && gi[k] < mi)) { m = v[k]; mi = gi[k]; }

    __syncthreads();

    for (int r = 0; r < TOPK; ++r) {
        float wm = m; int wmi = mi;
        #pragma unroll
        for (int off = 32; off > 0; off >>= 1) {
            float ov = __shfl_xor(wm, off, 64);
            int   oi = __shfl_xor(wmi, off, 64);
            if (ov > wm || (ov == wm && oi < wmi)) { wm = ov; wmi = oi; }
        }
        if (lane == 0) { wred_v[wave] = wm; wred_i[wave] = wmi; }
        __syncthreads();
        float gm = wred_v[0]; int gmi = wred_i[0];
        #pragma unroll
        for (int w = 1; w < 4; ++w) {
            float ov = wred_v[w]; int oi = wred_i[w];
            if (ov > gm || (ov == gm && oi < gmi)) { gm = ov; gmi = oi; }
        }
        if (t == 0) { tval[r] = gm; tidx[r] = gmi; }
        if (mi == gmi) {
            #pragma unroll
            for (int k = 0; k < 32; ++k)
                if (gi[k] == gmi) v[k] = -FLT_MAX;
            m = v[0]; mi = gi[0];
            #pragma unroll
            for (int k = 1; k < 32; ++k)
                if (v[k] > m || (v[k] == m && gi[k] < mi)) { m = v[k]; mi = gi[k]; }
        }
        __syncthreads();
    }

    const float scale = scale_s;
    float sum = 0.f;
    #pragma unroll
    for (int j = 0; j < TOPK; ++j) sum += expf((tval[j] - tval[0]) * scale);
    if (t < TOPK) attn_s[t] = expf((tval[t] - tval[0]) * scale) / sum;
    __syncthreads();

    if (t < TOPK) full_attn[tidx[t]] = attn_s[t];

    for (int d = t; d < DIM; d += 256) {
        float acc = 0.f;
        #pragma unroll
        for (int j = 0; j < TOPK; ++j)
            acc = fmaf(attn_s[j], Vm[(size_t)tidx[j] * DIM + d], acc);
        out[d] = acc;
    }
}

// ---------------------------------------------------------------------------
extern "C" void kernel_launch(void* const* d_in, const int* in_sizes, int n_in,
                              void* d_out, int out_size, void* d_ws, size_t ws_size,
                              hipStream_t stream) {
    const float* q  = (const float*)d_in[0];
    const float* Km = (const float*)d_in[1];
    const float* Vm = (const float*)d_in[2];

    float* out       = (float*)d_out;       // [0 .. 1024)
    float* full_attn = out + DIM;           // [1024 .. 1024+131072)

    float* logits   = (float*)d_ws;                 // NROWS floats
    float* cand_val = logits + NROWS;               // NCAND floats
    int*   cand_idx = (int*)(cand_val + NCAND);     // NCAND ints
    float* partial  = (float*)(cand_idx + NCAND);   // NROWS*64 floats = 33.5 MB

    logitsA_kernel<<<NWAVES / 4, 256, 0, stream>>>(Km, q, partial);
    reduceB_kernel<<<1024, 256, 0, stream>>>(partial, logits, full_attn);
    topk_local_kernel<<<NCHUNK, 64, 0, stream>>>(logits, cand_val, cand_idx);
    final_kernel<<<1, 256, 0, stream>>>(cand_val, cand_idx, q, Vm, out, full_attn);
}